// Round 1
// baseline (3157.445 us; speedup 1.0000x reference)
//
#include <hip/hip_runtime.h>

#define NUM_USER 100000
#define NUM_ITEM 50000
#define NNODE (NUM_USER + NUM_ITEM)
#define EMBED_DIM 64
#define NNZ_CNT 5000000
#define BATCH 4096
#define LAYERS 3

// One wave (64 lanes) per edge; lane = channel k.
// y[row[e]][k] += vals[e] * x[col[e]][k]
__global__ void spmm_atomic(const float* __restrict__ vals,
                            const int* __restrict__ row,
                            const int* __restrict__ col,
                            const float* __restrict__ x,
                            float* __restrict__ y) {
    const long long total = (long long)NNZ_CNT * 64;
    long long tid = (long long)blockIdx.x * blockDim.x + threadIdx.x;
    const long long stride = (long long)gridDim.x * blockDim.x;
    for (; tid < total; tid += stride) {
        const int e = (int)(tid >> 6);
        const int k = (int)(tid & 63);
        const float v = vals[e];          // wave-uniform broadcast
        const int c = col[e];
        const int r = row[e];
        const float xv = x[(long long)c * EMBED_DIM + k];   // coalesced 256B/wave
        atomicAdd(&y[(long long)r * EMBED_DIM + k], v * xv); // coalesced 256B/wave
    }
}

// Accumulate the gathered user/item rows of src into uacc/iacc ([BATCH,64]).
__global__ void gather_add(const float* __restrict__ src,
                           const int* __restrict__ users,
                           const int* __restrict__ items,
                           float* __restrict__ uacc,
                           float* __restrict__ iacc) {
    const int tid = blockIdx.x * blockDim.x + threadIdx.x; // BATCH*64 threads
    const int b = tid >> 6;
    const int k = tid & 63;
    const int u = users[b];                 // wave-uniform
    const int it = items[b] + NUM_USER;     // wave-uniform
    uacc[tid] += src[(long long)u * EMBED_DIM + k];
    iacc[tid] += src[(long long)it * EMBED_DIM + k];
}

// One wave per batch element: dot(uacc[b], iacc[b]) / 16.
__global__ void score_kernel(const float* __restrict__ uacc,
                             const float* __restrict__ iacc,
                             float* __restrict__ out) {
    const int tid = blockIdx.x * blockDim.x + threadIdx.x;
    const int b = tid >> 6;
    const int k = tid & 63;
    float p = uacc[tid] * iacc[tid];
    #pragma unroll
    for (int off = 32; off > 0; off >>= 1) p += __shfl_down(p, off, 64);
    if (k == 0) out[b] = p * (1.0f / 16.0f);
}

extern "C" void kernel_launch(void* const* d_in, const int* in_sizes, int n_in,
                              void* d_out, int out_size, void* d_ws, size_t ws_size,
                              hipStream_t stream) {
    const float* vals       = (const float*)d_in[0];
    const float* user_table = (const float*)d_in[1];
    const float* item_table = (const float*)d_in[2];
    const int*   row        = (const int*)d_in[3];
    const int*   col        = (const int*)d_in[4];
    const int*   users      = (const int*)d_in[5];
    const int*   items      = (const int*)d_in[6];
    float* out = (float*)d_out;

    char* ws = (char*)d_ws;
    const size_t NB = (size_t)NNODE * EMBED_DIM * sizeof(float);  // 38.4 MB
    float* buf0 = (float*)ws;
    float* buf1 = (float*)(ws + NB);
    float* uacc = (float*)(ws + 2 * NB);
    float* iacc = uacc + (size_t)BATCH * EMBED_DIM;

    // buf0 = concat(user_table, item_table)
    hipMemcpyAsync(buf0, user_table, (size_t)NUM_USER * EMBED_DIM * sizeof(float),
                   hipMemcpyDeviceToDevice, stream);
    hipMemcpyAsync(buf0 + (size_t)NUM_USER * EMBED_DIM, item_table,
                   (size_t)NUM_ITEM * EMBED_DIM * sizeof(float),
                   hipMemcpyDeviceToDevice, stream);

    // zero the small accumulators, then add hop-0 (the embedding itself)
    hipMemsetAsync(uacc, 0, 2 * (size_t)BATCH * EMBED_DIM * sizeof(float), stream);
    gather_add<<<(BATCH * EMBED_DIM) / 256, 256, 0, stream>>>(buf0, users, items, uacc, iacc);

    float* cur = buf0;
    float* nxt = buf1;
    for (int l = 0; l < LAYERS; ++l) {
        hipMemsetAsync(nxt, 0, NB, stream);
        spmm_atomic<<<4096, 256, 0, stream>>>(vals, row, col, cur, nxt);
        gather_add<<<(BATCH * EMBED_DIM) / 256, 256, 0, stream>>>(nxt, users, items, uacc, iacc);
        float* t = cur; cur = nxt; nxt = t;
    }

    score_kernel<<<(BATCH * EMBED_DIM) / 256, 256, 0, stream>>>(uacc, iacc, out);
}

// Round 2
// 1477.076 us; speedup vs baseline: 2.1376x; 2.1376x over previous
//
#include <hip/hip_runtime.h>

#define NUM_USER 100000
#define NUM_ITEM 50000
#define NNODE (NUM_USER + NUM_ITEM)
#define EMBED_DIM 64
#define NNZ_CNT 5000000
#define BATCH 4096

// ---------- CSR build ----------

__global__ void hist_kernel(const int* __restrict__ row, int* __restrict__ counts) {
    int tid = blockIdx.x * blockDim.x + threadIdx.x;
    const int stride = gridDim.x * blockDim.x;
    for (int e = tid; e < NNZ_CNT; e += stride)
        atomicAdd(&counts[row[e]], 1);
}

// Single workgroup exclusive scan over counts[NNODE] -> row_ptr, cursor.
__global__ void scan_kernel(const int* __restrict__ counts,
                            int* __restrict__ row_ptr,
                            int* __restrict__ cursor) {
    __shared__ int sums[1024];
    const int t = threadIdx.x;
    const int chunk = (NNODE + 1023) / 1024;           // 147
    const int lo = t * chunk;
    const int hi = min(lo + chunk, NNODE);
    int s = 0;
    for (int i = lo; i < hi; ++i) s += counts[i];
    sums[t] = s;
    __syncthreads();
    for (int off = 1; off < 1024; off <<= 1) {
        int v = (t >= off) ? sums[t - off] : 0;
        __syncthreads();
        sums[t] += v;
        __syncthreads();
    }
    int run = sums[t] - s;                              // exclusive prefix
    for (int i = lo; i < hi; ++i) {
        row_ptr[i] = run;
        cursor[i]  = run;
        run += counts[i];
    }
    if (t == 1023) row_ptr[NNODE] = sums[1023];
}

__global__ void scatter_kernel(const float* __restrict__ vals,
                               const int* __restrict__ row,
                               const int* __restrict__ col,
                               int* __restrict__ cursor,
                               int2* __restrict__ csr) {
    int tid = blockIdx.x * blockDim.x + threadIdx.x;
    const int stride = gridDim.x * blockDim.x;
    for (int e = tid; e < NNZ_CNT; e += stride) {
        const int r = row[e];
        const int pos = atomicAdd(&cursor[r], 1);
        csr[pos] = make_int2(col[e], __float_as_int(vals[e]));
    }
}

// ---------- pull-mode SpMM: one wave per row, lane = channel ----------

template <bool FROM_TABLES>
__global__ void spmm_pull(const int* __restrict__ row_ptr,
                          const int2* __restrict__ csr,
                          const float* __restrict__ xa,   // user_table or buf
                          const float* __restrict__ xb,   // item_table or unused
                          float* __restrict__ y) {
    const int wave = (int)((blockIdx.x * blockDim.x + threadIdx.x) >> 6);
    const int lane = threadIdx.x & 63;
    if (wave >= NNODE) return;
    const int start = row_ptr[wave];
    const int end   = row_ptr[wave + 1];
    float acc = 0.f;
    for (int base = start; base < end; base += 64) {
        const int n = min(64, end - base);
        int idx = base + lane;
        if (idx >= end) idx = end - 1;
        const int2 rec = csr[idx];                      // coalesced 512B/wave
        for (int j = 0; j < n; ++j) {
            const int   c = __builtin_amdgcn_readlane(rec.x, j);  // SGPR bcast
            const float v = __int_as_float(__builtin_amdgcn_readlane(rec.y, j));
            float xv;
            if (FROM_TABLES) {
                xv = (c < NUM_USER) ? xa[(size_t)c * EMBED_DIM + lane]
                                    : xb[(size_t)(c - NUM_USER) * EMBED_DIM + lane];
            } else {
                xv = xa[(size_t)c * EMBED_DIM + lane];  // coalesced 256B/wave
            }
            acc += v * xv;
        }
    }
    y[(size_t)wave * EMBED_DIM + lane] = acc;           // streamed, once per row
}

// Layer-3 restricted pull: one wave per (set, batch-slot), adds into acc bufs.
__global__ void batch_pull(const int* __restrict__ row_ptr,
                           const int2* __restrict__ csr,
                           const float* __restrict__ x,
                           const int* __restrict__ users,
                           const int* __restrict__ items,
                           float* __restrict__ uacc,
                           float* __restrict__ iacc) {
    const int g = (int)((blockIdx.x * blockDim.x + threadIdx.x) >> 6);
    const int lane = threadIdx.x & 63;
    if (g >= 2 * BATCH) return;
    const bool is_item = g >= BATCH;
    const int b = is_item ? g - BATCH : g;
    const int node = is_item ? items[b] + NUM_USER : users[b];
    const int start = row_ptr[node];
    const int end   = row_ptr[node + 1];
    float acc = 0.f;
    for (int base = start; base < end; base += 64) {
        const int n = min(64, end - base);
        int idx = base + lane;
        if (idx >= end) idx = end - 1;
        const int2 rec = csr[idx];
        for (int j = 0; j < n; ++j) {
            const int   c = __builtin_amdgcn_readlane(rec.x, j);
            const float v = __int_as_float(__builtin_amdgcn_readlane(rec.y, j));
            acc += v * x[(size_t)c * EMBED_DIM + lane];
        }
    }
    float* dst = is_item ? iacc : uacc;
    dst[(size_t)b * EMBED_DIM + lane] += acc;
}

// ---------- accumulators ----------

// hop-0: acc = gathered embedding tables
__global__ void init_acc(const float* __restrict__ user_table,
                         const float* __restrict__ item_table,
                         const int* __restrict__ users,
                         const int* __restrict__ items,
                         float* __restrict__ uacc,
                         float* __restrict__ iacc) {
    const int tid = blockIdx.x * blockDim.x + threadIdx.x;   // BATCH*64
    const int b = tid >> 6;
    const int k = tid & 63;
    uacc[tid] = user_table[(size_t)users[b] * EMBED_DIM + k];
    iacc[tid] = item_table[(size_t)items[b] * EMBED_DIM + k];
}

__global__ void gather_add(const float* __restrict__ src,
                           const int* __restrict__ users,
                           const int* __restrict__ items,
                           float* __restrict__ uacc,
                           float* __restrict__ iacc) {
    const int tid = blockIdx.x * blockDim.x + threadIdx.x;
    const int b = tid >> 6;
    const int k = tid & 63;
    uacc[tid] += src[(size_t)users[b] * EMBED_DIM + k];
    iacc[tid] += src[((size_t)items[b] + NUM_USER) * EMBED_DIM + k];
}

__global__ void score_kernel(const float* __restrict__ uacc,
                             const float* __restrict__ iacc,
                             float* __restrict__ out) {
    const int tid = blockIdx.x * blockDim.x + threadIdx.x;
    const int b = tid >> 6;
    const int k = tid & 63;
    float p = uacc[tid] * iacc[tid];
    #pragma unroll
    for (int off = 32; off > 0; off >>= 1) p += __shfl_down(p, off, 64);
    if (k == 0) out[b] = p * (1.0f / 16.0f);
}

// ---------- launch ----------

extern "C" void kernel_launch(void* const* d_in, const int* in_sizes, int n_in,
                              void* d_out, int out_size, void* d_ws, size_t ws_size,
                              hipStream_t stream) {
    const float* vals       = (const float*)d_in[0];
    const float* user_table = (const float*)d_in[1];
    const float* item_table = (const float*)d_in[2];
    const int*   row        = (const int*)d_in[3];
    const int*   col        = (const int*)d_in[4];
    const int*   users      = (const int*)d_in[5];
    const int*   items      = (const int*)d_in[6];
    float* out = (float*)d_out;

    char* ws = (char*)d_ws;
    const size_t NB = (size_t)NNODE * EMBED_DIM * sizeof(float);   // 38.4 MB
    size_t off = 0;
    auto alloc = [&](size_t bytes) { char* p = ws + off; off += (bytes + 255) & ~(size_t)255; return p; };
    float* bufA    = (float*)alloc(NB);
    float* bufB    = (float*)alloc(NB);
    int2*  csr     = (int2*)alloc((size_t)NNZ_CNT * sizeof(int2)); // 40 MB
    int*   row_ptr = (int*)alloc((size_t)(NNODE + 1) * sizeof(int));
    int*   cursor  = (int*)alloc((size_t)NNODE * sizeof(int));
    int*   counts  = (int*)alloc((size_t)NNODE * sizeof(int));
    float* uacc    = (float*)alloc((size_t)BATCH * EMBED_DIM * sizeof(float));
    float* iacc    = (float*)alloc((size_t)BATCH * EMBED_DIM * sizeof(float));

    // CSR build
    hipMemsetAsync(counts, 0, (size_t)NNODE * sizeof(int), stream);
    hist_kernel<<<1024, 256, 0, stream>>>(row, counts);
    scan_kernel<<<1, 1024, 0, stream>>>(counts, row_ptr, cursor);
    scatter_kernel<<<2048, 256, 0, stream>>>(vals, row, col, cursor, csr);

    // hop 0
    init_acc<<<(BATCH * EMBED_DIM) / 256, 256, 0, stream>>>(user_table, item_table,
                                                            users, items, uacc, iacc);
    // hop 1 (full N)
    spmm_pull<true><<<(NNODE + 3) / 4, 256, 0, stream>>>(row_ptr, csr, user_table,
                                                         item_table, bufA);
    gather_add<<<(BATCH * EMBED_DIM) / 256, 256, 0, stream>>>(bufA, users, items, uacc, iacc);
    // hop 2 (full N)
    spmm_pull<false><<<(NNODE + 3) / 4, 256, 0, stream>>>(row_ptr, csr, bufA, bufA, bufB);
    gather_add<<<(BATCH * EMBED_DIM) / 256, 256, 0, stream>>>(bufB, users, items, uacc, iacc);
    // hop 3 (restricted to batch rows)
    batch_pull<<<(2 * BATCH * 64) / 256, 256, 0, stream>>>(row_ptr, csr, bufB,
                                                           users, items, uacc, iacc);
    // scores
    score_kernel<<<(BATCH * EMBED_DIM) / 256, 256, 0, stream>>>(uacc, iacc, out);
}

// Round 3
// 716.537 us; speedup vs baseline: 4.4065x; 2.0614x over previous
//
#include <hip/hip_runtime.h>

#define NUM_USER 100000
#define NUM_ITEM 50000
#define NNODE 150000
#define EMBED_DIM 64
#define NNZ_CNT 5000000
#define BATCH 4096

#define BROWS 128
#define NBUCK ((NNODE + BROWS - 1) / BROWS)     // 1172
#define NBLK_H 256
#define NBLK_S 512
#define CHUNK_S ((NNZ_CNT + NBLK_S - 1) / NBLK_S) // 9766
#define COLMASK 0x3FFFF                          // 18 bits, col < 262144

// ---------- bucket-hierarchical CSR build ----------

// Per-block LDS histogram over 1172 buckets, then one global atomic per bucket.
__global__ void bhist(const int* __restrict__ row, int* __restrict__ bcount) {
    __shared__ int lh[NBUCK];
    for (int i = threadIdx.x; i < NBUCK; i += blockDim.x) lh[i] = 0;
    __syncthreads();
    int tid = blockIdx.x * blockDim.x + threadIdx.x;
    const int stride = gridDim.x * blockDim.x;
    for (int e = tid; e < NNZ_CNT; e += stride)
        atomicAdd(&lh[row[e] >> 7], 1);
    __syncthreads();
    for (int i = threadIdx.x; i < NBUCK; i += blockDim.x)
        if (lh[i]) atomicAdd(&bcount[i], lh[i]);
}

// Single-WG exclusive scan over 1172 bucket counts.
__global__ void bscan(const int* __restrict__ bcount,
                      int* __restrict__ bptr, int* __restrict__ gcur) {
    __shared__ int sums[1024];
    const int t = threadIdx.x;
    const int chunk = (NBUCK + 1023) / 1024;      // 2
    const int lo = t * chunk;
    const int hi = min(lo + chunk, NBUCK);
    int s = 0;
    for (int i = lo; i < hi; ++i) s += bcount[i];
    sums[t] = s;
    __syncthreads();
    for (int off = 1; off < 1024; off <<= 1) {
        int v = (t >= off) ? sums[t - off] : 0;
        __syncthreads();
        sums[t] += v;
        __syncthreads();
    }
    int run = sums[t] - s;
    for (int i = lo; i < hi; ++i) { bptr[i] = run; gcur[i] = run; run += bcount[i]; }
    if (t == 1023) bptr[NBUCK] = NNZ_CNT;
}

// Per-block: LDS re-hist -> one base atomic per (block,bucket) -> LDS-cursor scatter.
__global__ void bscatter(const float* __restrict__ vals,
                         const int* __restrict__ row,
                         const int* __restrict__ col,
                         int* __restrict__ gcur,
                         int2* __restrict__ grouped) {
    __shared__ int lh[NBUCK];
    const int lo = blockIdx.x * CHUNK_S;
    const int hi = min(lo + CHUNK_S, NNZ_CNT);
    for (int i = threadIdx.x; i < NBUCK; i += blockDim.x) lh[i] = 0;
    __syncthreads();
    for (int e = lo + (int)threadIdx.x; e < hi; e += blockDim.x)
        atomicAdd(&lh[row[e] >> 7], 1);
    __syncthreads();
    for (int i = threadIdx.x; i < NBUCK; i += blockDim.x) {
        const int h = lh[i];
        lh[i] = h ? atomicAdd(&gcur[i], h) : 0;
    }
    __syncthreads();
    for (int e = lo + (int)threadIdx.x; e < hi; e += blockDim.x) {
        const int r = row[e];
        const int bk = r >> 7;
        const int rl = r & 127;
        const int pos = atomicAdd(&lh[bk], 1);
        grouped[pos] = make_int2(col[e] | (rl << 18), __float_as_int(vals[e]));
    }
}

// One WG per bucket: LDS 128-bin hist + scan -> exact row_ptr + contiguous CSR.
__global__ void bucket_sort(const int* __restrict__ bptr,
                            const int2* __restrict__ grouped,
                            int2* __restrict__ csr,
                            int* __restrict__ row_ptr) {
    __shared__ int lh[BROWS];
    __shared__ int lbase[BROWS];
    const int b = blockIdx.x;
    const int bstart = bptr[b];
    const int bend   = bptr[b + 1];
    if (threadIdx.x < BROWS) lh[threadIdx.x] = 0;
    __syncthreads();
    for (int e = bstart + (int)threadIdx.x; e < bend; e += blockDim.x)
        atomicAdd(&lh[((unsigned)grouped[e].x) >> 18], 1);
    __syncthreads();
    if (threadIdx.x == 0) {
        int run = 0;
        for (int i = 0; i < BROWS; ++i) { const int c = lh[i]; lbase[i] = run; run += c; }
    }
    __syncthreads();
    const int node = b * BROWS + (int)threadIdx.x;
    if (threadIdx.x < BROWS && node < NNODE) row_ptr[node] = bstart + lbase[threadIdx.x];
    if (threadIdx.x < BROWS) lh[threadIdx.x] = lbase[threadIdx.x];
    __syncthreads();
    for (int e = bstart + (int)threadIdx.x; e < bend; e += blockDim.x) {
        const int2 rec = grouped[e];
        const int rl = ((unsigned)rec.x) >> 18;
        const int pos = bstart + atomicAdd(&lh[rl], 1);
        csr[pos] = make_int2(rec.x & COLMASK, rec.y);
    }
}

__global__ void fix_tail(int* __restrict__ row_ptr) {
    row_ptr[NNODE] = NNZ_CNT;
}

// ---------- pull-mode SpMM: one wave per row, lane = channel ----------

template <bool FROM_TABLES>
__global__ void spmm_pull(const int* __restrict__ row_ptr,
                          const int2* __restrict__ csr,
                          const float* __restrict__ xa,
                          const float* __restrict__ xb,
                          float* __restrict__ y) {
    const int wave = (int)((blockIdx.x * blockDim.x + threadIdx.x) >> 6);
    const int lane = threadIdx.x & 63;
    if (wave >= NNODE) return;
    const int start = row_ptr[wave];
    const int end   = row_ptr[wave + 1];
    float acc = 0.f;
    for (int base = start; base < end; base += 64) {
        const int n = min(64, end - base);
        int idx = base + lane;
        if (idx >= end) idx = end - 1;
        const int2 rec = csr[idx];
        for (int j = 0; j < n; ++j) {
            const int   c = __builtin_amdgcn_readlane(rec.x, j);
            const float v = __int_as_float(__builtin_amdgcn_readlane(rec.y, j));
            float xv;
            if (FROM_TABLES) {
                xv = (c < NUM_USER) ? xa[(size_t)c * EMBED_DIM + lane]
                                    : xb[(size_t)(c - NUM_USER) * EMBED_DIM + lane];
            } else {
                xv = xa[(size_t)c * EMBED_DIM + lane];
            }
            acc += v * xv;
        }
    }
    y[(size_t)wave * EMBED_DIM + lane] = acc;
}

// Layer-3 restricted pull for the 8192 batch rows only.
__global__ void batch_pull(const int* __restrict__ row_ptr,
                           const int2* __restrict__ csr,
                           const float* __restrict__ x,
                           const int* __restrict__ users,
                           const int* __restrict__ items,
                           float* __restrict__ uacc,
                           float* __restrict__ iacc) {
    const int g = (int)((blockIdx.x * blockDim.x + threadIdx.x) >> 6);
    const int lane = threadIdx.x & 63;
    if (g >= 2 * BATCH) return;
    const bool is_item = g >= BATCH;
    const int b = is_item ? g - BATCH : g;
    const int node = is_item ? items[b] + NUM_USER : users[b];
    const int start = row_ptr[node];
    const int end   = row_ptr[node + 1];
    float acc = 0.f;
    for (int base = start; base < end; base += 64) {
        const int n = min(64, end - base);
        int idx = base + lane;
        if (idx >= end) idx = end - 1;
        const int2 rec = csr[idx];
        for (int j = 0; j < n; ++j) {
            const int   c = __builtin_amdgcn_readlane(rec.x, j);
            const float v = __int_as_float(__builtin_amdgcn_readlane(rec.y, j));
            acc += v * x[(size_t)c * EMBED_DIM + lane];
        }
    }
    float* dst = is_item ? iacc : uacc;
    dst[(size_t)b * EMBED_DIM + lane] += acc;
}

// ---------- accumulators / scoring ----------

__global__ void init_acc(const float* __restrict__ user_table,
                         const float* __restrict__ item_table,
                         const int* __restrict__ users,
                         const int* __restrict__ items,
                         float* __restrict__ uacc,
                         float* __restrict__ iacc) {
    const int tid = blockIdx.x * blockDim.x + threadIdx.x;
    const int b = tid >> 6;
    const int k = tid & 63;
    uacc[tid] = user_table[(size_t)users[b] * EMBED_DIM + k];
    iacc[tid] = item_table[(size_t)items[b] * EMBED_DIM + k];
}

__global__ void gather_add(const float* __restrict__ src,
                           const int* __restrict__ users,
                           const int* __restrict__ items,
                           float* __restrict__ uacc,
                           float* __restrict__ iacc) {
    const int tid = blockIdx.x * blockDim.x + threadIdx.x;
    const int b = tid >> 6;
    const int k = tid & 63;
    uacc[tid] += src[(size_t)users[b] * EMBED_DIM + k];
    iacc[tid] += src[((size_t)items[b] + NUM_USER) * EMBED_DIM + k];
}

__global__ void score_kernel(const float* __restrict__ uacc,
                             const float* __restrict__ iacc,
                             float* __restrict__ out) {
    const int tid = blockIdx.x * blockDim.x + threadIdx.x;
    const int b = tid >> 6;
    const int k = tid & 63;
    float p = uacc[tid] * iacc[tid];
    #pragma unroll
    for (int off = 32; off > 0; off >>= 1) p += __shfl_down(p, off, 64);
    if (k == 0) out[b] = p * (1.0f / 16.0f);
}

// ---------- launch ----------

extern "C" void kernel_launch(void* const* d_in, const int* in_sizes, int n_in,
                              void* d_out, int out_size, void* d_ws, size_t ws_size,
                              hipStream_t stream) {
    const float* vals       = (const float*)d_in[0];
    const float* user_table = (const float*)d_in[1];
    const float* item_table = (const float*)d_in[2];
    const int*   row        = (const int*)d_in[3];
    const int*   col        = (const int*)d_in[4];
    const int*   users      = (const int*)d_in[5];
    const int*   items      = (const int*)d_in[6];
    float* out = (float*)d_out;

    char* ws = (char*)d_ws;
    size_t off = 0;
    auto alloc = [&](size_t bytes) { char* p = ws + off; off += (bytes + 255) & ~(size_t)255; return p; };
    const size_t NB = (size_t)NNODE * EMBED_DIM * sizeof(float);       // 38.4 MB
    float* bufA    = (float*)alloc(NB);
    int2*  grouped = (int2*)alloc((size_t)NNZ_CNT * sizeof(int2));     // 40 MB (reused as bufB)
    int2*  csr     = (int2*)alloc((size_t)NNZ_CNT * sizeof(int2));     // 40 MB
    int*   row_ptr = (int*)alloc((size_t)(NNODE + 1) * sizeof(int));
    int*   bptr    = (int*)alloc((size_t)(NBUCK + 1) * sizeof(int));
    int*   gcur    = (int*)alloc((size_t)NBUCK * sizeof(int));
    int*   bcount  = (int*)alloc((size_t)NBUCK * sizeof(int));
    float* uacc    = (float*)alloc((size_t)BATCH * EMBED_DIM * sizeof(float));
    float* iacc    = (float*)alloc((size_t)BATCH * EMBED_DIM * sizeof(float));

    // CSR build (bucket-hierarchical)
    hipMemsetAsync(bcount, 0, (size_t)NBUCK * sizeof(int), stream);
    bhist<<<NBLK_H, 256, 0, stream>>>(row, bcount);
    bscan<<<1, 1024, 0, stream>>>(bcount, bptr, gcur);
    bscatter<<<NBLK_S, 256, 0, stream>>>(vals, row, col, gcur, grouped);
    bucket_sort<<<NBUCK, 256, 0, stream>>>(bptr, grouped, csr, row_ptr);
    fix_tail<<<1, 1, 0, stream>>>(row_ptr);

    // hop 0
    init_acc<<<(BATCH * EMBED_DIM) / 256, 256, 0, stream>>>(user_table, item_table,
                                                            users, items, uacc, iacc);
    // hop 1 (full N, read tables directly)
    spmm_pull<true><<<(NNODE + 3) / 4, 256, 0, stream>>>(row_ptr, csr, user_table,
                                                         item_table, bufA);
    gather_add<<<(BATCH * EMBED_DIM) / 256, 256, 0, stream>>>(bufA, users, items, uacc, iacc);
    // hop 2 (full N); output aliases `grouped`, which is dead after bucket_sort
    float* bufB = (float*)grouped;
    spmm_pull<false><<<(NNODE + 3) / 4, 256, 0, stream>>>(row_ptr, csr, bufA, bufA, bufB);
    gather_add<<<(BATCH * EMBED_DIM) / 256, 256, 0, stream>>>(bufB, users, items, uacc, iacc);
    // hop 3 (restricted to the 8192 batch rows)
    batch_pull<<<(2 * BATCH * 64) / 256, 256, 0, stream>>>(row_ptr, csr, bufB,
                                                           users, items, uacc, iacc);
    // scores
    score_kernel<<<(BATCH * EMBED_DIM) / 256, 256, 0, stream>>>(uacc, iacc, out);
}

// Round 4
// 511.829 us; speedup vs baseline: 6.1689x; 1.4000x over previous
//
#include <hip/hip_runtime.h>

#define NUM_USER 100000
#define NUM_ITEM 50000
#define NNODE 150000
#define EMBED_DIM 64
#define NNZ_CNT 5000000
#define BATCH 4096

#define BROWS 128
#define NBUCK ((NNODE + BROWS - 1) / BROWS)     // 1172
#define NBLK_H 256
#define NBLK_S 512
#define CHUNK_S ((NNZ_CNT + NBLK_S - 1) / NBLK_S) // 9766
#define COLMASK 0x3FFFF                          // 18 bits, col < 262144

// ---------- bucket-hierarchical CSR build ----------

// Per-block LDS histogram over 1172 buckets, then one global atomic per bucket.
__global__ void bhist(const int* __restrict__ row, int* __restrict__ bcount) {
    __shared__ int lh[NBUCK];
    for (int i = threadIdx.x; i < NBUCK; i += blockDim.x) lh[i] = 0;
    __syncthreads();
    int tid = blockIdx.x * blockDim.x + threadIdx.x;
    const int stride = gridDim.x * blockDim.x;
    for (int e = tid; e < NNZ_CNT; e += stride)
        atomicAdd(&lh[row[e] >> 7], 1);
    __syncthreads();
    for (int i = threadIdx.x; i < NBUCK; i += blockDim.x)
        if (lh[i]) atomicAdd(&bcount[i], lh[i]);
}

// Single-WG exclusive scan over 1172 bucket counts.
__global__ void bscan(const int* __restrict__ bcount,
                      int* __restrict__ bptr, int* __restrict__ gcur) {
    __shared__ int sums[1024];
    const int t = threadIdx.x;
    const int chunk = (NBUCK + 1023) / 1024;      // 2
    const int lo = t * chunk;
    const int hi = min(lo + chunk, NBUCK);
    int s = 0;
    for (int i = lo; i < hi; ++i) s += bcount[i];
    sums[t] = s;
    __syncthreads();
    for (int off = 1; off < 1024; off <<= 1) {
        int v = (t >= off) ? sums[t - off] : 0;
        __syncthreads();
        sums[t] += v;
        __syncthreads();
    }
    int run = sums[t] - s;
    for (int i = lo; i < hi; ++i) { bptr[i] = run; gcur[i] = run; run += bcount[i]; }
    if (t == 1023) bptr[NBUCK] = NNZ_CNT;
}

// Per-block: LDS re-hist -> one base atomic per (block,bucket) -> LDS-cursor scatter.
__global__ void bscatter(const float* __restrict__ vals,
                         const int* __restrict__ row,
                         const int* __restrict__ col,
                         int* __restrict__ gcur,
                         int2* __restrict__ grouped) {
    __shared__ int lh[NBUCK];
    const int lo = blockIdx.x * CHUNK_S;
    const int hi = min(lo + CHUNK_S, NNZ_CNT);
    for (int i = threadIdx.x; i < NBUCK; i += blockDim.x) lh[i] = 0;
    __syncthreads();
    for (int e = lo + (int)threadIdx.x; e < hi; e += blockDim.x)
        atomicAdd(&lh[row[e] >> 7], 1);
    __syncthreads();
    for (int i = threadIdx.x; i < NBUCK; i += blockDim.x) {
        const int h = lh[i];
        lh[i] = h ? atomicAdd(&gcur[i], h) : 0;
    }
    __syncthreads();
    for (int e = lo + (int)threadIdx.x; e < hi; e += blockDim.x) {
        const int r = row[e];
        const int bk = r >> 7;
        const int rl = r & 127;
        const int pos = atomicAdd(&lh[bk], 1);
        grouped[pos] = make_int2(col[e] | (rl << 18), __float_as_int(vals[e]));
    }
}

// One WG per bucket: LDS 128-bin hist + scan -> exact row_ptr + contiguous CSR.
__global__ void bucket_sort(const int* __restrict__ bptr,
                            const int2* __restrict__ grouped,
                            int2* __restrict__ csr,
                            int* __restrict__ row_ptr) {
    __shared__ int lh[BROWS];
    __shared__ int lbase[BROWS];
    const int b = blockIdx.x;
    const int bstart = bptr[b];
    const int bend   = bptr[b + 1];
    if (threadIdx.x < BROWS) lh[threadIdx.x] = 0;
    __syncthreads();
    for (int e = bstart + (int)threadIdx.x; e < bend; e += blockDim.x)
        atomicAdd(&lh[((unsigned)grouped[e].x) >> 18], 1);
    __syncthreads();
    if (threadIdx.x == 0) {
        int run = 0;
        for (int i = 0; i < BROWS; ++i) { const int c = lh[i]; lbase[i] = run; run += c; }
    }
    __syncthreads();
    const int node = b * BROWS + (int)threadIdx.x;
    if (threadIdx.x < BROWS && node < NNODE) row_ptr[node] = bstart + lbase[threadIdx.x];
    if (threadIdx.x < BROWS) lh[threadIdx.x] = lbase[threadIdx.x];
    __syncthreads();
    for (int e = bstart + (int)threadIdx.x; e < bend; e += blockDim.x) {
        const int2 rec = grouped[e];
        const int rl = ((unsigned)rec.x) >> 18;
        const int pos = bstart + atomicAdd(&lh[rl], 1);
        csr[pos] = make_int2(rec.x & COLMASK, rec.y);
    }
}

__global__ void fix_tail(int* __restrict__ row_ptr) {
    row_ptr[NNODE] = NNZ_CNT;
}

// ---------- pull-mode SpMM: one wave per row, lane = channel ----------
// 8-deep gather unroll: 8 outstanding x-loads per wave (latency hiding).

template <bool FROM_TABLES>
__global__ __launch_bounds__(256) void spmm_pull(const int* __restrict__ row_ptr,
                          const int2* __restrict__ csr,
                          const float* __restrict__ xa,
                          const float* __restrict__ xb,
                          float* __restrict__ y) {
    const int wave = (int)((blockIdx.x * blockDim.x + threadIdx.x) >> 6);
    const int lane = threadIdx.x & 63;
    if (wave >= NNODE) return;
    const int start = row_ptr[wave];
    const int end   = row_ptr[wave + 1];
    float acc = 0.f;
    for (int base = start; base < end; base += 64) {
        const int n = min(64, end - base);
        int idx = base + lane;
        if (idx >= end) idx = end - 1;
        const int2 rec = csr[idx];
        int j = 0;
        for (; j + 8 <= n; j += 8) {
            float vv[8], xv[8];
            #pragma unroll
            for (int u = 0; u < 8; ++u) {
                const int c = __builtin_amdgcn_readlane(rec.x, j + u);
                vv[u] = __int_as_float(__builtin_amdgcn_readlane(rec.y, j + u));
                if (FROM_TABLES) {
                    xv[u] = (c < NUM_USER) ? xa[(size_t)c * EMBED_DIM + lane]
                                           : xb[(size_t)(c - NUM_USER) * EMBED_DIM + lane];
                } else {
                    xv[u] = xa[(size_t)c * EMBED_DIM + lane];
                }
            }
            #pragma unroll
            for (int u = 0; u < 8; ++u) acc += vv[u] * xv[u];
        }
        for (; j < n; ++j) {
            const int c = __builtin_amdgcn_readlane(rec.x, j);
            const float v = __int_as_float(__builtin_amdgcn_readlane(rec.y, j));
            float xv;
            if (FROM_TABLES) {
                xv = (c < NUM_USER) ? xa[(size_t)c * EMBED_DIM + lane]
                                    : xb[(size_t)(c - NUM_USER) * EMBED_DIM + lane];
            } else {
                xv = xa[(size_t)c * EMBED_DIM + lane];
            }
            acc += v * xv;
        }
    }
    y[(size_t)wave * EMBED_DIM + lane] = acc;
}

// Layer-3 restricted pull for the 8192 batch rows only (same unroll).
__global__ __launch_bounds__(256) void batch_pull(const int* __restrict__ row_ptr,
                           const int2* __restrict__ csr,
                           const float* __restrict__ x,
                           const int* __restrict__ users,
                           const int* __restrict__ items,
                           float* __restrict__ uacc,
                           float* __restrict__ iacc) {
    const int g = (int)((blockIdx.x * blockDim.x + threadIdx.x) >> 6);
    const int lane = threadIdx.x & 63;
    if (g >= 2 * BATCH) return;
    const bool is_item = g >= BATCH;
    const int b = is_item ? g - BATCH : g;
    const int node = is_item ? items[b] + NUM_USER : users[b];
    const int start = row_ptr[node];
    const int end   = row_ptr[node + 1];
    float acc = 0.f;
    for (int base = start; base < end; base += 64) {
        const int n = min(64, end - base);
        int idx = base + lane;
        if (idx >= end) idx = end - 1;
        const int2 rec = csr[idx];
        int j = 0;
        for (; j + 8 <= n; j += 8) {
            float vv[8], xv[8];
            #pragma unroll
            for (int u = 0; u < 8; ++u) {
                const int c = __builtin_amdgcn_readlane(rec.x, j + u);
                vv[u] = __int_as_float(__builtin_amdgcn_readlane(rec.y, j + u));
                xv[u] = x[(size_t)c * EMBED_DIM + lane];
            }
            #pragma unroll
            for (int u = 0; u < 8; ++u) acc += vv[u] * xv[u];
        }
        for (; j < n; ++j) {
            const int c = __builtin_amdgcn_readlane(rec.x, j);
            const float v = __int_as_float(__builtin_amdgcn_readlane(rec.y, j));
            acc += v * x[(size_t)c * EMBED_DIM + lane];
        }
    }
    float* dst = is_item ? iacc : uacc;
    dst[(size_t)b * EMBED_DIM + lane] += acc;
}

// ---------- accumulators / scoring ----------

__global__ void init_acc(const float* __restrict__ user_table,
                         const float* __restrict__ item_table,
                         const int* __restrict__ users,
                         const int* __restrict__ items,
                         float* __restrict__ uacc,
                         float* __restrict__ iacc) {
    const int tid = blockIdx.x * blockDim.x + threadIdx.x;
    const int b = tid >> 6;
    const int k = tid & 63;
    uacc[tid] = user_table[(size_t)users[b] * EMBED_DIM + k];
    iacc[tid] = item_table[(size_t)items[b] * EMBED_DIM + k];
}

__global__ void gather_add(const float* __restrict__ src,
                           const int* __restrict__ users,
                           const int* __restrict__ items,
                           float* __restrict__ uacc,
                           float* __restrict__ iacc) {
    const int tid = blockIdx.x * blockDim.x + threadIdx.x;
    const int b = tid >> 6;
    const int k = tid & 63;
    uacc[tid] += src[(size_t)users[b] * EMBED_DIM + k];
    iacc[tid] += src[((size_t)items[b] + NUM_USER) * EMBED_DIM + k];
}

__global__ void score_kernel(const float* __restrict__ uacc,
                             const float* __restrict__ iacc,
                             float* __restrict__ out) {
    const int tid = blockIdx.x * blockDim.x + threadIdx.x;
    const int b = tid >> 6;
    const int k = tid & 63;
    float p = uacc[tid] * iacc[tid];
    #pragma unroll
    for (int off = 32; off > 0; off >>= 1) p += __shfl_down(p, off, 64);
    if (k == 0) out[b] = p * (1.0f / 16.0f);
}

// ---------- launch ----------

extern "C" void kernel_launch(void* const* d_in, const int* in_sizes, int n_in,
                              void* d_out, int out_size, void* d_ws, size_t ws_size,
                              hipStream_t stream) {
    const float* vals       = (const float*)d_in[0];
    const float* user_table = (const float*)d_in[1];
    const float* item_table = (const float*)d_in[2];
    const int*   row        = (const int*)d_in[3];
    const int*   col        = (const int*)d_in[4];
    const int*   users      = (const int*)d_in[5];
    const int*   items      = (const int*)d_in[6];
    float* out = (float*)d_out;

    char* ws = (char*)d_ws;
    size_t off = 0;
    auto alloc = [&](size_t bytes) { char* p = ws + off; off += (bytes + 255) & ~(size_t)255; return p; };
    const size_t NB = (size_t)NNODE * EMBED_DIM * sizeof(float);       // 38.4 MB
    float* bufA    = (float*)alloc(NB);
    int2*  grouped = (int2*)alloc((size_t)NNZ_CNT * sizeof(int2));     // 40 MB (reused as bufB)
    int2*  csr     = (int2*)alloc((size_t)NNZ_CNT * sizeof(int2));     // 40 MB
    int*   row_ptr = (int*)alloc((size_t)(NNODE + 1) * sizeof(int));
    int*   bptr    = (int*)alloc((size_t)(NBUCK + 1) * sizeof(int));
    int*   gcur    = (int*)alloc((size_t)NBUCK * sizeof(int));
    int*   bcount  = (int*)alloc((size_t)NBUCK * sizeof(int));
    float* uacc    = (float*)alloc((size_t)BATCH * EMBED_DIM * sizeof(float));
    float* iacc    = (float*)alloc((size_t)BATCH * EMBED_DIM * sizeof(float));

    // CSR build (bucket-hierarchical)
    hipMemsetAsync(bcount, 0, (size_t)NBUCK * sizeof(int), stream);
    bhist<<<NBLK_H, 256, 0, stream>>>(row, bcount);
    bscan<<<1, 1024, 0, stream>>>(bcount, bptr, gcur);
    bscatter<<<NBLK_S, 256, 0, stream>>>(vals, row, col, gcur, grouped);
    bucket_sort<<<NBUCK, 256, 0, stream>>>(bptr, grouped, csr, row_ptr);
    fix_tail<<<1, 1, 0, stream>>>(row_ptr);

    // hop 0
    init_acc<<<(BATCH * EMBED_DIM) / 256, 256, 0, stream>>>(user_table, item_table,
                                                            users, items, uacc, iacc);
    // hop 1 (full N, read tables directly)
    spmm_pull<true><<<(NNODE + 3) / 4, 256, 0, stream>>>(row_ptr, csr, user_table,
                                                         item_table, bufA);
    gather_add<<<(BATCH * EMBED_DIM) / 256, 256, 0, stream>>>(bufA, users, items, uacc, iacc);
    // hop 2 (full N); output aliases `grouped`, which is dead after bucket_sort
    float* bufB = (float*)grouped;
    spmm_pull<false><<<(NNODE + 3) / 4, 256, 0, stream>>>(row_ptr, csr, bufA, bufA, bufB);
    gather_add<<<(BATCH * EMBED_DIM) / 256, 256, 0, stream>>>(bufB, users, items, uacc, iacc);
    // hop 3 (restricted to the 8192 batch rows)
    batch_pull<<<(2 * BATCH * 64) / 256, 256, 0, stream>>>(row_ptr, csr, bufB,
                                                           users, items, uacc, iacc);
    // scores
    score_kernel<<<(BATCH * EMBED_DIM) / 256, 256, 0, stream>>>(uacc, iacc, out);
}

// Round 5
// 397.014 us; speedup vs baseline: 7.9530x; 1.2892x over previous
//
#include <hip/hip_runtime.h>

#define NUM_USER 100000
#define NUM_ITEM 50000
#define NNODE 150000
#define EMBED_DIM 64
#define NNZ_CNT 5000000
#define BATCH 4096

#define BROWS 128
#define NBUCK ((NNODE + BROWS - 1) / BROWS)     // 1172
#define NBLK_H 256
#define NBLK_S 512
#define CHUNK_S ((NNZ_CNT + NBLK_S - 1) / NBLK_S) // 9766
#define COLMASK 0x3FFFF                          // 18 bits, col < 262144

__device__ __forceinline__ unsigned short f2bf(float f) {
    unsigned b = __float_as_uint(f);
    return (unsigned short)((b + 0x7FFFu + ((b >> 16) & 1u)) >> 16);  // RNE
}
__device__ __forceinline__ float bf2f(unsigned short u) {
    return __uint_as_float((unsigned)u << 16);
}

// ---------- bucket-hierarchical CSR build ----------

__global__ void bhist(const int* __restrict__ row, int* __restrict__ bcount) {
    __shared__ int lh[NBUCK];
    for (int i = threadIdx.x; i < NBUCK; i += blockDim.x) lh[i] = 0;
    __syncthreads();
    int tid = blockIdx.x * blockDim.x + threadIdx.x;
    const int stride = gridDim.x * blockDim.x;
    for (int e = tid; e < NNZ_CNT; e += stride)
        atomicAdd(&lh[row[e] >> 7], 1);
    __syncthreads();
    for (int i = threadIdx.x; i < NBUCK; i += blockDim.x)
        if (lh[i]) atomicAdd(&bcount[i], lh[i]);
}

__global__ void bscan(const int* __restrict__ bcount,
                      int* __restrict__ bptr, int* __restrict__ gcur) {
    __shared__ int sums[1024];
    const int t = threadIdx.x;
    const int chunk = (NBUCK + 1023) / 1024;      // 2
    const int lo = t * chunk;
    const int hi = min(lo + chunk, NBUCK);
    int s = 0;
    for (int i = lo; i < hi; ++i) s += bcount[i];
    sums[t] = s;
    __syncthreads();
    for (int off = 1; off < 1024; off <<= 1) {
        int v = (t >= off) ? sums[t - off] : 0;
        __syncthreads();
        sums[t] += v;
        __syncthreads();
    }
    int run = sums[t] - s;
    for (int i = lo; i < hi; ++i) { bptr[i] = run; gcur[i] = run; run += bcount[i]; }
    if (t == 1023) bptr[NBUCK] = NNZ_CNT;
}

__global__ void bscatter(const float* __restrict__ vals,
                         const int* __restrict__ row,
                         const int* __restrict__ col,
                         int* __restrict__ gcur,
                         int2* __restrict__ grouped) {
    __shared__ int lh[NBUCK];
    const int lo = blockIdx.x * CHUNK_S;
    const int hi = min(lo + CHUNK_S, NNZ_CNT);
    for (int i = threadIdx.x; i < NBUCK; i += blockDim.x) lh[i] = 0;
    __syncthreads();
    for (int e = lo + (int)threadIdx.x; e < hi; e += blockDim.x)
        atomicAdd(&lh[row[e] >> 7], 1);
    __syncthreads();
    for (int i = threadIdx.x; i < NBUCK; i += blockDim.x) {
        const int h = lh[i];
        lh[i] = h ? atomicAdd(&gcur[i], h) : 0;
    }
    __syncthreads();
    for (int e = lo + (int)threadIdx.x; e < hi; e += blockDim.x) {
        const int r = row[e];
        const int bk = r >> 7;
        const int rl = r & 127;
        const int pos = atomicAdd(&lh[bk], 1);
        grouped[pos] = make_int2(col[e] | (rl << 18), __float_as_int(vals[e]));
    }
}

__global__ void bucket_sort(const int* __restrict__ bptr,
                            const int2* __restrict__ grouped,
                            int2* __restrict__ csr,
                            int* __restrict__ row_ptr) {
    __shared__ int lh[BROWS];
    __shared__ int lbase[BROWS];
    const int b = blockIdx.x;
    const int bstart = bptr[b];
    const int bend   = bptr[b + 1];
    if (threadIdx.x < BROWS) lh[threadIdx.x] = 0;
    __syncthreads();
    for (int e = bstart + (int)threadIdx.x; e < bend; e += blockDim.x)
        atomicAdd(&lh[((unsigned)grouped[e].x) >> 18], 1);
    __syncthreads();
    if (threadIdx.x == 0) {
        int run = 0;
        for (int i = 0; i < BROWS; ++i) { const int c = lh[i]; lbase[i] = run; run += c; }
    }
    __syncthreads();
    const int node = b * BROWS + (int)threadIdx.x;
    if (threadIdx.x < BROWS && node < NNODE) row_ptr[node] = bstart + lbase[threadIdx.x];
    if (threadIdx.x < BROWS) lh[threadIdx.x] = lbase[threadIdx.x];
    __syncthreads();
    for (int e = bstart + (int)threadIdx.x; e < bend; e += blockDim.x) {
        const int2 rec = grouped[e];
        const int rl = ((unsigned)rec.x) >> 18;
        const int pos = bstart + atomicAdd(&lh[rl], 1);
        csr[pos] = make_int2(rec.x & COLMASK, rec.y);
    }
}

__global__ void fix_tail(int* __restrict__ row_ptr) {
    row_ptr[NNODE] = NNZ_CNT;
}

// ---------- table concat -> bf16 ----------

__global__ void to_bf16(const float4* __restrict__ ut, const float4* __restrict__ it,
                        ushort4* __restrict__ xbf) {
    const int nu4 = NUM_USER * EMBED_DIM / 4;
    const int nt4 = NNODE * EMBED_DIM / 4;
    int i = blockIdx.x * blockDim.x + threadIdx.x;
    const int stride = gridDim.x * blockDim.x;
    for (; i < nt4; i += stride) {
        const float4 v = (i < nu4) ? ut[i] : it[i - nu4];
        ushort4 o;
        o.x = f2bf(v.x); o.y = f2bf(v.y); o.z = f2bf(v.z); o.w = f2bf(v.w);
        xbf[i] = o;
    }
}

// ---------- pull-mode SpMM (bf16 in / bf16 out) ----------
// One wave per row, lane = channel. CSR stream read via wave-uniform
// (readfirstlane-anchored) indices -> scalar s_load; 8 outstanding gathers.

__global__ __launch_bounds__(256) void spmm_pull(const int* __restrict__ row_ptr,
                          const int2* __restrict__ csr,
                          const unsigned short* __restrict__ x,
                          unsigned short* __restrict__ y) {
    const int wave = (int)((blockIdx.x * blockDim.x + threadIdx.x) >> 6);
    const int lane = threadIdx.x & 63;
    if (wave >= NNODE) return;
    const int start = __builtin_amdgcn_readfirstlane(row_ptr[wave]);
    const int end   = __builtin_amdgcn_readfirstlane(row_ptr[wave + 1]);
    float acc = 0.f;
    int j = start;
    for (; j + 8 <= end; j += 8) {
        float vv[8], xv[8];
        #pragma unroll
        for (int u = 0; u < 8; ++u) {
            int2 rec; __builtin_memcpy(&rec, &csr[j + u], 8);   // uniform -> s_load
            vv[u] = __int_as_float(rec.y);
            xv[u] = bf2f(x[(size_t)rec.x * EMBED_DIM + lane]);  // 128B/wave gather
        }
        #pragma unroll
        for (int u = 0; u < 8; ++u) acc += vv[u] * xv[u];
    }
    for (; j < end; ++j) {
        int2 rec; __builtin_memcpy(&rec, &csr[j], 8);
        acc += __int_as_float(rec.y) * bf2f(x[(size_t)rec.x * EMBED_DIM + lane]);
    }
    y[(size_t)wave * EMBED_DIM + lane] = f2bf(acc);
}

// Layer-3 restricted pull for the 8192 batch rows only.
__global__ __launch_bounds__(256) void batch_pull(const int* __restrict__ row_ptr,
                           const int2* __restrict__ csr,
                           const unsigned short* __restrict__ x,
                           const int* __restrict__ users,
                           const int* __restrict__ items,
                           float* __restrict__ uacc,
                           float* __restrict__ iacc) {
    const int g = (int)((blockIdx.x * blockDim.x + threadIdx.x) >> 6);
    const int lane = threadIdx.x & 63;
    if (g >= 2 * BATCH) return;
    const bool is_item = g >= BATCH;
    const int b = is_item ? g - BATCH : g;
    const int node = is_item ? items[b] + NUM_USER : users[b];
    const int start = __builtin_amdgcn_readfirstlane(row_ptr[node]);
    const int end   = __builtin_amdgcn_readfirstlane(row_ptr[node + 1]);
    float acc = 0.f;
    int j = start;
    for (; j + 8 <= end; j += 8) {
        float vv[8], xv[8];
        #pragma unroll
        for (int u = 0; u < 8; ++u) {
            int2 rec; __builtin_memcpy(&rec, &csr[j + u], 8);
            vv[u] = __int_as_float(rec.y);
            xv[u] = bf2f(x[(size_t)rec.x * EMBED_DIM + lane]);
        }
        #pragma unroll
        for (int u = 0; u < 8; ++u) acc += vv[u] * xv[u];
    }
    for (; j < end; ++j) {
        int2 rec; __builtin_memcpy(&rec, &csr[j], 8);
        acc += __int_as_float(rec.y) * bf2f(x[(size_t)rec.x * EMBED_DIM + lane]);
    }
    float* dst = is_item ? iacc : uacc;
    dst[(size_t)b * EMBED_DIM + lane] += acc;
}

// ---------- accumulators / scoring ----------

__global__ void init_acc(const float* __restrict__ user_table,
                         const float* __restrict__ item_table,
                         const int* __restrict__ users,
                         const int* __restrict__ items,
                         float* __restrict__ uacc,
                         float* __restrict__ iacc) {
    const int tid = blockIdx.x * blockDim.x + threadIdx.x;
    const int b = tid >> 6;
    const int k = tid & 63;
    uacc[tid] = user_table[(size_t)users[b] * EMBED_DIM + k];
    iacc[tid] = item_table[(size_t)items[b] * EMBED_DIM + k];
}

__global__ void gather_add(const unsigned short* __restrict__ src,
                           const int* __restrict__ users,
                           const int* __restrict__ items,
                           float* __restrict__ uacc,
                           float* __restrict__ iacc) {
    const int tid = blockIdx.x * blockDim.x + threadIdx.x;
    const int b = tid >> 6;
    const int k = tid & 63;
    uacc[tid] += bf2f(src[(size_t)users[b] * EMBED_DIM + k]);
    iacc[tid] += bf2f(src[((size_t)items[b] + NUM_USER) * EMBED_DIM + k]);
}

__global__ void score_kernel(const float* __restrict__ uacc,
                             const float* __restrict__ iacc,
                             float* __restrict__ out) {
    const int tid = blockIdx.x * blockDim.x + threadIdx.x;
    const int b = tid >> 6;
    const int k = tid & 63;
    float p = uacc[tid] * iacc[tid];
    #pragma unroll
    for (int off = 32; off > 0; off >>= 1) p += __shfl_down(p, off, 64);
    if (k == 0) out[b] = p * (1.0f / 16.0f);
}

// ---------- launch ----------

extern "C" void kernel_launch(void* const* d_in, const int* in_sizes, int n_in,
                              void* d_out, int out_size, void* d_ws, size_t ws_size,
                              hipStream_t stream) {
    const float* vals       = (const float*)d_in[0];
    const float* user_table = (const float*)d_in[1];
    const float* item_table = (const float*)d_in[2];
    const int*   row        = (const int*)d_in[3];
    const int*   col        = (const int*)d_in[4];
    const int*   users      = (const int*)d_in[5];
    const int*   items      = (const int*)d_in[6];
    float* out = (float*)d_out;

    char* ws = (char*)d_ws;
    size_t off = 0;
    auto alloc = [&](size_t bytes) { char* p = ws + off; off += (bytes + 255) & ~(size_t)255; return p; };
    const size_t NBH = (size_t)NNODE * EMBED_DIM * sizeof(unsigned short); // 19.2 MB
    unsigned short* xbf  = (unsigned short*)alloc(NBH);
    unsigned short* bufA = (unsigned short*)alloc(NBH);
    int2*  grouped = (int2*)alloc((size_t)NNZ_CNT * sizeof(int2));   // 40 MB (bufB aliases)
    int2*  csr     = (int2*)alloc((size_t)NNZ_CNT * sizeof(int2));   // 40 MB
    int*   row_ptr = (int*)alloc((size_t)(NNODE + 1) * sizeof(int));
    int*   bptr    = (int*)alloc((size_t)(NBUCK + 1) * sizeof(int));
    int*   gcur    = (int*)alloc((size_t)NBUCK * sizeof(int));
    int*   bcount  = (int*)alloc((size_t)NBUCK * sizeof(int));
    float* uacc    = (float*)alloc((size_t)BATCH * EMBED_DIM * sizeof(float));
    float* iacc    = (float*)alloc((size_t)BATCH * EMBED_DIM * sizeof(float));

    // CSR build (bucket-hierarchical)
    hipMemsetAsync(bcount, 0, (size_t)NBUCK * sizeof(int), stream);
    bhist<<<NBLK_H, 256, 0, stream>>>(row, bcount);
    bscan<<<1, 1024, 0, stream>>>(bcount, bptr, gcur);
    bscatter<<<NBLK_S, 256, 0, stream>>>(vals, row, col, gcur, grouped);
    bucket_sort<<<NBUCK, 256, 0, stream>>>(bptr, grouped, csr, row_ptr);
    fix_tail<<<1, 1, 0, stream>>>(row_ptr);

    // concat tables -> bf16
    to_bf16<<<2048, 256, 0, stream>>>((const float4*)user_table,
                                      (const float4*)item_table, (ushort4*)xbf);

    // hop 0
    init_acc<<<(BATCH * EMBED_DIM) / 256, 256, 0, stream>>>(user_table, item_table,
                                                            users, items, uacc, iacc);
    // hop 1 (full N)
    spmm_pull<<<(NNODE + 3) / 4, 256, 0, stream>>>(row_ptr, csr, xbf, bufA);
    gather_add<<<(BATCH * EMBED_DIM) / 256, 256, 0, stream>>>(bufA, users, items, uacc, iacc);
    // hop 2 (full N); output aliases `grouped` (dead after bucket_sort)
    unsigned short* bufB = (unsigned short*)grouped;
    spmm_pull<<<(NNODE + 3) / 4, 256, 0, stream>>>(row_ptr, csr, bufA, bufB);
    gather_add<<<(BATCH * EMBED_DIM) / 256, 256, 0, stream>>>(bufB, users, items, uacc, iacc);
    // hop 3 (restricted to the 8192 batch rows)
    batch_pull<<<(2 * BATCH * 64) / 256, 256, 0, stream>>>(row_ptr, csr, bufB,
                                                           users, items, uacc, iacc);
    // scores
    score_kernel<<<(BATCH * EMBED_DIM) / 256, 256, 0, stream>>>(uacc, iacc, out);
}